// Round 12
// baseline (200.314 us; speedup 1.0000x reference)
//
#include <hip/hip_runtime.h>
#include <hip/hip_fp16.h>
#include <cstdint>

#define VOCAB 50000
#define EMB   300
#define SEQ   80
#define HID   128
#define BATCH 4096

typedef __attribute__((ext_vector_type(8))) _Float16 f16x8;
typedef __attribute__((ext_vector_type(4))) float    f32x4;

static __device__ __forceinline__ float fast_tanh(float xv) {
    const float e = __expf(2.f * xv);
    float r;
    asm("v_rcp_f32 %0, %1" : "=v"(r) : "v"(e + 1.f));
    return fmaf(-2.f, r, 1.f);
}
static __device__ __forceinline__ unsigned pack2h(float a, float b) {
    _Float16 ha = (_Float16)a, hb = (_Float16)b;
    unsigned short ua, ub;
    __builtin_memcpy(&ua, &ha, 2); __builtin_memcpy(&ub, &hb, 2);
    return (unsigned)ua | ((unsigned)ub << 16);
}

// ---------------------------------------------------------------------------
// k_wprep: fragment tables.
//  W2 (chunks 0..5119): c=(ks,col,g): W2[c][j] = Wxh[32ks+8g+j][col] (0-pad)
//  W3 (chunks 0..2047): SIGMA-PERMUTED Whh A-frags (HW-verified R10/R11):
//   c2=(ct,ks,lane): W3[c2][j] =
//     Whh[32ks + 16*(j>>2) + 4*(lane>>4) + (j&3)][16ct + (lane&15)]
// ---------------------------------------------------------------------------
__global__ __launch_bounds__(256) void k_wprep(const float* __restrict__ Wxh,
                                               const float* __restrict__ Whh,
                                               _Float16* __restrict__ W2,
                                               _Float16* __restrict__ W3) {
    const int c = blockIdx.x * 256 + threadIdx.x;
    if (c < 5120) {
        const int ks = c >> 9, rem = c & 511, col = rem >> 2, g = rem & 3;
        f16x8 f;
        #pragma unroll
        for (int j = 0; j < 8; ++j) {
            const int k = 32 * ks + 8 * g + j;
            f[j] = (_Float16)(k < EMB ? Wxh[k * HID + col] : 0.f);
        }
        *reinterpret_cast<f16x8*>(W2 + (size_t)c * 8) = f;
    } else if (c < 7168) {
        const int c2 = c - 5120;
        const int ct = c2 >> 8, ks = (c2 >> 6) & 3, l = c2 & 63;
        const int g = l >> 4, r16 = l & 15;
        f16x8 f;
        #pragma unroll
        for (int j = 0; j < 8; ++j) {
            const int sig = 32 * ks + 16 * (j >> 2) + 4 * g + (j & 3);
            f[j] = (_Float16)Whh[sig * HID + 16 * ct + r16];
        }
        *reinterpret_cast<f16x8*>(W3 + (size_t)c2 * 8) = f;
    }
}

// ---------------------------------------------------------------------------
// k_ptab: P[v][c] = f32( emb[v] @ Wxh + bh ). BARRIER-FREE (unchanged).
// ---------------------------------------------------------------------------
__global__ __launch_bounds__(256, 2) void k_ptab(
    const float*    __restrict__ emb,  // [VOCAB][300]
    const _Float16* __restrict__ W2,   // Wxh frag table
    const float*    __restrict__ bh,   // [128]
    float*          __restrict__ P)    // [VOCAB][128] f32
{
    const int tid = threadIdx.x, lane = tid & 63;
    const int wv = tid >> 6, r16 = lane & 15, g = lane >> 4;
    const int row = blockIdx.x * 64 + wv * 16 + r16;
    const float* rp = emb + (size_t)(row < VOCAB ? row : VOCAB - 1) * EMB;
    const bool wr = (row < VOCAB);

    f16x8 ef[10];
    #pragma unroll
    for (int ks = 0; ks < 9; ++ks) {
        const float4 u0 = *reinterpret_cast<const float4*>(rp + 32 * ks + 8 * g);
        const float4 u1 = *reinterpret_cast<const float4*>(rp + 32 * ks + 8 * g + 4);
        f16x8 f;
        f[0] = (_Float16)u0.x; f[1] = (_Float16)u0.y;
        f[2] = (_Float16)u0.z; f[3] = (_Float16)u0.w;
        f[4] = (_Float16)u1.x; f[5] = (_Float16)u1.y;
        f[6] = (_Float16)u1.z; f[7] = (_Float16)u1.w;
        ef[ks] = f;
    }
    {
        f16x8 f;
        #pragma unroll
        for (int j = 0; j < 8; ++j) f[j] = (_Float16)0.f;
        if (g == 0) {
            const float4 u0 = *reinterpret_cast<const float4*>(rp + 288);
            const float4 u1 = *reinterpret_cast<const float4*>(rp + 292);
            f[0] = (_Float16)u0.x; f[1] = (_Float16)u0.y;
            f[2] = (_Float16)u0.z; f[3] = (_Float16)u0.w;
            f[4] = (_Float16)u1.x; f[5] = (_Float16)u1.y;
            f[6] = (_Float16)u1.z; f[7] = (_Float16)u1.w;
        } else if (g == 1) {
            const float4 u0 = *reinterpret_cast<const float4*>(rp + 296);
            f[0] = (_Float16)u0.x; f[1] = (_Float16)u0.y;
            f[2] = (_Float16)u0.z; f[3] = (_Float16)u0.w;
        }
        ef[9] = f;
    }

    float4 bhf[8];
    #pragma unroll
    for (int ct = 0; ct < 8; ++ct)
        bhf[ct] = *reinterpret_cast<const float4*>(bh + 16 * ct + 4 * g);

    f16x8 wA[10], wB[10];
    #pragma unroll
    for (int ks = 0; ks < 10; ++ks)
        wA[ks] = *reinterpret_cast<const f16x8*>(
            W2 + ((size_t)ks * 512 + (size_t)r16 * 4 + g) * 8);

    float* const po = P + (size_t)(wr ? row : 0) * HID;

    #pragma unroll
    for (int ct = 0; ct < 8; ++ct) {
        if (ct < 7) {
            const int coln = 16 * (ct + 1) + r16;
            #pragma unroll
            for (int ks = 0; ks < 10; ++ks)
                ((ct & 1) ? wA : wB)[ks] = *reinterpret_cast<const f16x8*>(
                    W2 + ((size_t)ks * 512 + (size_t)coln * 4 + g) * 8);
        }
        const f16x8* wc = (ct & 1) ? wB : wA;
        f32x4 a0 = {0.f, 0.f, 0.f, 0.f}, a1 = {0.f, 0.f, 0.f, 0.f};
        #pragma unroll
        for (int ks = 0; ks < 10; ks += 2) {
            a0 = __builtin_amdgcn_mfma_f32_16x16x32_f16(wc[ks],     ef[ks],     a0, 0, 0, 0);
            a1 = __builtin_amdgcn_mfma_f32_16x16x32_f16(wc[ks + 1], ef[ks + 1], a1, 0, 0, 0);
        }
        float4 o;
        o.x = a0[0] + a1[0] + bhf[ct].x;
        o.y = a0[1] + a1[1] + bhf[ct].y;
        o.z = a0[2] + a1[2] + bhf[ct].z;
        o.w = a0[3] + a1[3] + bhf[ct].w;
        if (wr) *reinterpret_cast<float4*>(po + ct * 16 + g * 4) = o;
    }
}

// ---------------------------------------------------------------------------
// k_rnn: 8 INDEPENDENT waves per 512-thr block (one 16-row group each; zero
// barriers, zero loop-LDS) -> 2 waves/SIMD so stalls of one chain are hidden
// by the sibling wave. Whh sigma-frags in registers; xp gather (f32, C-init)
// single-buffered with ~1-step lead; index pipeline depth 2.
// launch_bounds(512,2) caps at 256 VGPR (fits ~234 live).
// ---------------------------------------------------------------------------
__global__ __launch_bounds__(512, 2) void k_rnn(
    const int*      __restrict__ x,    // [BATCH][SEQ]
    const float*    __restrict__ P,    // [VOCAB][128] f32 (bh folded)
    const _Float16* __restrict__ W3,   // sigma-permuted Whh frag table
    const float*    __restrict__ Wd,   // [128]
    const float*    __restrict__ bd,   // [1]
    float*          __restrict__ out)  // [BATCH]
{
    const int tid  = threadIdx.x;
    const int lane = tid & 63;
    const int wv   = tid >> 6;                  // 0..7: independent group
    const int r16 = lane & 15, g = lane >> 4;
    const int rb = (blockIdx.x * 8 + wv) * 16;  // this wave's 16 batch rows
    const int xbase = (rb + r16) * SEQ;

    // ---- Whh fragments resident in registers ----
    f16x8 wh[8][4];
    #pragma unroll
    for (int ct = 0; ct < 8; ++ct)
        #pragma unroll
        for (int ks = 0; ks < 4; ++ks)
            wh[ct][ks] = *reinterpret_cast<const f16x8*>(
                W3 + ((size_t)(ct * 4 + ks) * 64 + lane) * 8);

    // ---- h0 = 0 B-frags ----
    f16x8 hf[4];
    {
        f16x8 hz;
        #pragma unroll
        for (int j = 0; j < 8; ++j) hz[j] = (_Float16)0.f;
        hf[0] = hz; hf[1] = hz; hf[2] = hz; hf[3] = hz;
    }

    // ---- index pipeline (depth 2) + single xp gather buffer ----
    int idxA = x[xbase + 0];
    f32x4 xc[8];
    {
        const float* p0 = P + (size_t)idxA * HID + 4 * g;
        #pragma unroll
        for (int ct = 0; ct < 8; ++ct)
            xc[ct] = *reinterpret_cast<const f32x4*>(p0 + 16 * ct);
    }
    idxA = x[xbase + 1];
    int idxB = x[xbase + 2];

    f32x4 acc[8];

#define RNN_STEP(T)                                                            \
    {                                                                          \
        /* ks=0: C-init directly from gathered xp (no VALU) */                 \
        _Pragma("unroll")                                                      \
        for (int ct = 0; ct < 8; ++ct)                                         \
            acc[ct] = __builtin_amdgcn_mfma_f32_16x16x32_f16(                  \
                wh[ct][0], hf[0], xc[ct], 0, 0, 0);                            \
        /* xc now dead: refill with gather(T+1); rotate index pipeline */      \
        if ((T) + 1 < SEQ) {                                                   \
            const float* pp = P + (size_t)idxA * HID + 4 * g;                  \
            _Pragma("unroll")                                                  \
            for (int ct = 0; ct < 8; ++ct)                                     \
                xc[ct] = *reinterpret_cast<const f32x4*>(pp + 16 * ct);        \
            idxA = idxB;                                                       \
            if ((T) + 3 < SEQ) idxB = x[xbase + (T) + 3];                      \
        }                                                                      \
        _Pragma("unroll")                                                      \
        for (int ks = 1; ks < 4; ++ks)                                         \
            _Pragma("unroll")                                                  \
            for (int ct = 0; ct < 8; ++ct)                                     \
                acc[ct] = __builtin_amdgcn_mfma_f32_16x16x32_f16(              \
                    wh[ct][ks], hf[ks], acc[ct], 0, 0, 0);                     \
        _Pragma("unroll")                                                      \
        for (int ct = 0; ct < 8; ++ct) {                                       \
            acc[ct][0] = fast_tanh(acc[ct][0]);                                \
            acc[ct][1] = fast_tanh(acc[ct][1]);                                \
            acc[ct][2] = fast_tanh(acc[ct][2]);                                \
            acc[ct][3] = fast_tanh(acc[ct][3]);                                \
        }                                                                      \
        _Pragma("unroll")                                                      \
        for (int ks = 0; ks < 4; ++ks) {  /* sigma: lane-local repack */       \
            uint4 hu;                                                          \
            hu.x = pack2h(acc[2 * ks][0],     acc[2 * ks][1]);                 \
            hu.y = pack2h(acc[2 * ks][2],     acc[2 * ks][3]);                 \
            hu.z = pack2h(acc[2 * ks + 1][0], acc[2 * ks + 1][1]);             \
            hu.w = pack2h(acc[2 * ks + 1][2], acc[2 * ks + 1][3]);             \
            __builtin_memcpy(&hf[ks], &hu, 16);                                \
        }                                                                      \
    }

    #pragma unroll 1
    for (int t = 0; t < SEQ; ++t) {
        RNN_STEP(t)
    }
#undef RNN_STEP

    // ---- final dense + sigmoid from f32 h(79) in registers (acc) ----
    float part = 0.f;
    #pragma unroll
    for (int ct = 0; ct < 8; ++ct) {
        const float4 wd = *reinterpret_cast<const float4*>(Wd + 16 * ct + 4 * g);
        part += acc[ct][0] * wd.x + acc[ct][1] * wd.y
              + acc[ct][2] * wd.z + acc[ct][3] * wd.w;
    }
    part += __shfl_xor(part, 16, 64);
    part += __shfl_xor(part, 32, 64);
    if (lane < 16) out[rb + r16] = 1.f / (1.f + expf(-(part + bd[0])));
}

// ---------------------------------------------------------------------------
extern "C" void kernel_launch(void* const* d_in, const int* in_sizes, int n_in,
                              void* d_out, int out_size, void* d_ws, size_t ws_size,
                              hipStream_t stream)
{
    (void)in_sizes; (void)n_in; (void)out_size; (void)ws_size;
    const int*   x   = (const int*)  d_in[0];
    const float* emb = (const float*)d_in[1];
    const float* Wxh = (const float*)d_in[2];
    const float* Whh = (const float*)d_in[3];
    const float* bh  = (const float*)d_in[4];
    const float* Wd  = (const float*)d_in[5];
    const float* bd  = (const float*)d_in[6];
    float* out = (float*)d_out;

    float*    P  = (float*)d_ws;                               // 25.6 MB f32
    _Float16* W2 = (_Float16*)((char*)d_ws + 25600000);        // 80 KB
    _Float16* W3 = (_Float16*)((char*)d_ws + 25681920);        // 32 KB

    k_wprep<<<28, 256, 0, stream>>>(Wxh, Whh, W2, W3);
    k_ptab<<<(VOCAB + 63) / 64, 256, 0, stream>>>(emb, W2, bh, P);
    k_rnn<<<BATCH / 128, 512, 0, stream>>>(x, P, W3, Wd, bd, out);
}

// Round 13
// 81.652 us; speedup vs baseline: 2.4533x; 2.4533x over previous
//
#include <hip/hip_runtime.h>
#include <hip/hip_fp16.h>
#include <cstdint>

#define VOCAB 50000
#define EMB   300
#define SEQ   80
#define HID   128
#define BATCH 4096

typedef __attribute__((ext_vector_type(8))) _Float16 f16x8;
typedef __attribute__((ext_vector_type(4))) float    f32x4;

static __device__ __forceinline__ float fast_tanh(float xv) {
    const float e = __expf(2.f * xv);
    float r;
    asm("v_rcp_f32 %0, %1" : "=v"(r) : "v"(e + 1.f));
    return fmaf(-2.f, r, 1.f);
}
static __device__ __forceinline__ float f16b2f(unsigned short u) {
    _Float16 h; __builtin_memcpy(&h, &u, 2); return (float)h;
}
static __device__ __forceinline__ unsigned pack2h(float a, float b) {
    _Float16 ha = (_Float16)a, hb = (_Float16)b;
    unsigned short ua, ub;
    __builtin_memcpy(&ua, &ha, 2); __builtin_memcpy(&ub, &hb, 2);
    return (unsigned)ua | ((unsigned)ub << 16);
}

// ---------------------------------------------------------------------------
// k_wprep: fragment-ordered fp16 Wxh table (for k_ptab).
//  c=(ks,col,g): W2[c][j] = Wxh[32ks+8g+j][col], zero-padded past K=300.
// ---------------------------------------------------------------------------
__global__ __launch_bounds__(256) void k_wprep(const float* __restrict__ Wxh,
                                               _Float16* __restrict__ W2) {
    const int c = blockIdx.x * 256 + threadIdx.x;
    if (c >= 5120) return;
    const int ks = c >> 9, rem = c & 511, col = rem >> 2, g = rem & 3;
    f16x8 f;
    #pragma unroll
    for (int j = 0; j < 8; ++j) {
        const int k = 32 * ks + 8 * g + j;
        f[j] = (_Float16)(k < EMB ? Wxh[k * HID + col] : 0.f);
    }
    *reinterpret_cast<f16x8*>(W2 + (size_t)c * 8) = f;
}

// ---------------------------------------------------------------------------
// k_ptab: P[v][c] = f32( emb[v] @ Wxh + bh ). BARRIER-FREE (R10, verified).
// 256 thr / 4 independent waves; wave owns 16 rows x ALL 128 cols.
// ---------------------------------------------------------------------------
__global__ __launch_bounds__(256, 2) void k_ptab(
    const float*    __restrict__ emb,  // [VOCAB][300]
    const _Float16* __restrict__ W2,   // Wxh frag table
    const float*    __restrict__ bh,   // [128]
    float*          __restrict__ P)    // [VOCAB][128] f32
{
    const int tid = threadIdx.x, lane = tid & 63;
    const int wv = tid >> 6, r16 = lane & 15, g = lane >> 4;
    const int row = blockIdx.x * 64 + wv * 16 + r16;
    const float* rp = emb + (size_t)(row < VOCAB ? row : VOCAB - 1) * EMB;
    const bool wr = (row < VOCAB);

    f16x8 ef[10];
    #pragma unroll
    for (int ks = 0; ks < 9; ++ks) {
        const float4 u0 = *reinterpret_cast<const float4*>(rp + 32 * ks + 8 * g);
        const float4 u1 = *reinterpret_cast<const float4*>(rp + 32 * ks + 8 * g + 4);
        f16x8 f;
        f[0] = (_Float16)u0.x; f[1] = (_Float16)u0.y;
        f[2] = (_Float16)u0.z; f[3] = (_Float16)u0.w;
        f[4] = (_Float16)u1.x; f[5] = (_Float16)u1.y;
        f[6] = (_Float16)u1.z; f[7] = (_Float16)u1.w;
        ef[ks] = f;
    }
    {
        f16x8 f;
        #pragma unroll
        for (int j = 0; j < 8; ++j) f[j] = (_Float16)0.f;
        if (g == 0) {
            const float4 u0 = *reinterpret_cast<const float4*>(rp + 288);
            const float4 u1 = *reinterpret_cast<const float4*>(rp + 292);
            f[0] = (_Float16)u0.x; f[1] = (_Float16)u0.y;
            f[2] = (_Float16)u0.z; f[3] = (_Float16)u0.w;
            f[4] = (_Float16)u1.x; f[5] = (_Float16)u1.y;
            f[6] = (_Float16)u1.z; f[7] = (_Float16)u1.w;
        } else if (g == 1) {
            const float4 u0 = *reinterpret_cast<const float4*>(rp + 296);
            f[0] = (_Float16)u0.x; f[1] = (_Float16)u0.y;
            f[2] = (_Float16)u0.z; f[3] = (_Float16)u0.w;
        }
        ef[9] = f;
    }

    float4 bhf[8];
    #pragma unroll
    for (int ct = 0; ct < 8; ++ct)
        bhf[ct] = *reinterpret_cast<const float4*>(bh + 16 * ct + 4 * g);

    f16x8 wA[10], wB[10];
    #pragma unroll
    for (int ks = 0; ks < 10; ++ks)
        wA[ks] = *reinterpret_cast<const f16x8*>(
            W2 + ((size_t)ks * 512 + (size_t)r16 * 4 + g) * 8);

    float* const po = P + (size_t)(wr ? row : 0) * HID;

    #pragma unroll
    for (int ct = 0; ct < 8; ++ct) {
        if (ct < 7) {
            const int coln = 16 * (ct + 1) + r16;
            #pragma unroll
            for (int ks = 0; ks < 10; ++ks)
                ((ct & 1) ? wA : wB)[ks] = *reinterpret_cast<const f16x8*>(
                    W2 + ((size_t)ks * 512 + (size_t)coln * 4 + g) * 8);
        }
        const f16x8* wc = (ct & 1) ? wB : wA;
        f32x4 a0 = {0.f, 0.f, 0.f, 0.f}, a1 = {0.f, 0.f, 0.f, 0.f};
        #pragma unroll
        for (int ks = 0; ks < 10; ks += 2) {
            a0 = __builtin_amdgcn_mfma_f32_16x16x32_f16(wc[ks],     ef[ks],     a0, 0, 0, 0);
            a1 = __builtin_amdgcn_mfma_f32_16x16x32_f16(wc[ks + 1], ef[ks + 1], a1, 0, 0, 0);
        }
        float4 o;
        o.x = a0[0] + a1[0] + bhf[ct].x;
        o.y = a0[1] + a1[1] + bhf[ct].y;
        o.z = a0[2] + a1[2] + bhf[ct].z;
        o.w = a0[3] + a1[3] + bhf[ct].w;
        if (wr) *reinterpret_cast<float4*>(po + ct * 16 + g * 4) = o;
    }
}

// ---------------------------------------------------------------------------
// k_rnn: R7 structure (best measured: 1241 cyc/step), minus the Xbuf LDS
// staging. 512 thr / 8 waves per block, block owns 16 batch rows, wave owns
// 16 cols; grid 256 -> 8 waves/CU (2/SIMD). Per step/wave: xp C-init from
// register gather (f32 float4 from P, issued 2 steps ahead; idx pipeline
// depth 4 in registers -- all vmcnt-domain, nothing added to the lgkm/
// barrier path), 4 ds_read_b128 h-frags, 4 MFMA (2 chains), 4 tanh,
// 1 ds_write_b64, ONE lgkm-only barrier. Swapped-operand MFMA (R7-verified):
//   mfma(wh[ks], h_frag[ks], C) -> D lane (g,r16) reg r =
//   h_new[batch row r16][col 16wv+4g+r].
// ---------------------------------------------------------------------------
__global__ __launch_bounds__(512, 2) void k_rnn(
    const int*   __restrict__ x,    // [BATCH][SEQ]
    const float* __restrict__ P,    // [VOCAB][128] f32 (bh folded)
    const float* __restrict__ Whh,  // [128][128]
    const float* __restrict__ Wd,   // [128]
    const float* __restrict__ bd,   // [1]
    float*       __restrict__ out)  // [BATCH]
{
    __shared__ __align__(16) unsigned char Hb[2][16 * 256];  // h fp16, 2 x 4 KB

    const int tid = threadIdx.x, lane = tid & 63, wv = tid >> 6;
    const int r16 = lane & 15, g = lane >> 4;
    const int rb = blockIdx.x * 16;
    const int xbase = (rb + r16) * SEQ;

    if (tid < 256) { uint4 z = {}; *reinterpret_cast<uint4*>(&Hb[0][tid * 16]) = z; }

    const int col = 16 * wv + r16;

    // ---- t-invariant LDS offsets (R7-verified) ----
    int h_rd[4];
    #pragma unroll
    for (int ks = 0; ks < 4; ++ks)
        h_rd[ks] = r16 * 256 + (((4 * ks + g) ^ r16) & 15) * 16;
    const int hw = r16 * 256 + (((2 * wv + (g >> 1)) ^ r16) & 15) * 16 + (g & 1) * 8;

    // ---- Whh B-fragments in registers (one-time strided loads) ----
    f16x8 wh[4];
    #pragma unroll
    for (int ks = 0; ks < 4; ++ks) {
        f16x8 f;
        #pragma unroll
        for (int j = 0; j < 8; ++j)
            f[j] = (_Float16)Whh[(32 * ks + 8 * g + j) * HID + col];
        wh[ks] = f;
    }

    // ---- xp gather pipeline: depth-2 float4 buffers + depth-4 idx regs ----
    // lane (g,r16) needs P[idx(t)][16wv+4g .. +3] as its C-init.
    const int goff = 16 * wv + 4 * g;
    f32x4 xgA, xgB;
    int idxA, idxB;
    {
        const int i0 = x[xbase + 0];
        const int i1 = x[xbase + 1];
        xgA = *reinterpret_cast<const f32x4*>(P + (size_t)i0 * HID + goff);
        xgB = *reinterpret_cast<const f32x4*>(P + (size_t)i1 * HID + goff);
        idxA = x[xbase + 2];
        idxB = x[xbase + 3];
    }

    __syncthreads();  // zeroed Hb[0] visible

    const f32x4 z4 = {0.f, 0.f, 0.f, 0.f};
    f32x4 accA, accB;

#define STEP(T, PB, XG, IDX)                                                       \
    {                                                                              \
        const unsigned char* hb = &Hb[PB][0];                                      \
        const f16x8 h0 = *reinterpret_cast<const f16x8*>(hb + h_rd[0]);            \
        const f16x8 h1 = *reinterpret_cast<const f16x8*>(hb + h_rd[1]);            \
        const f16x8 h2 = *reinterpret_cast<const f16x8*>(hb + h_rd[2]);            \
        const f16x8 h3 = *reinterpret_cast<const f16x8*>(hb + h_rd[3]);            \
        accA = __builtin_amdgcn_mfma_f32_16x16x32_f16(wh[0], h0, XG, 0, 0, 0);     \
        accB = __builtin_amdgcn_mfma_f32_16x16x32_f16(wh[1], h1, z4, 0, 0, 0);     \
        accA = __builtin_amdgcn_mfma_f32_16x16x32_f16(wh[2], h2, accA, 0, 0, 0);   \
        accB = __builtin_amdgcn_mfma_f32_16x16x32_f16(wh[3], h3, accB, 0, 0, 0);   \
        /* XG consumed: refill with xp(T+2); rotate idx pipeline (T+4) */          \
        if ((T) + 2 < SEQ) {                                                       \
            XG = *reinterpret_cast<const f32x4*>(P + (size_t)(IDX) * HID + goff);  \
            if ((T) + 4 < SEQ) IDX = x[xbase + (T) + 4];                           \
        }                                                                          \
        uint2 hv;                                                                  \
        hv.x = pack2h(fast_tanh(accA[0] + accB[0]), fast_tanh(accA[1] + accB[1])); \
        hv.y = pack2h(fast_tanh(accA[2] + accB[2]), fast_tanh(accA[3] + accB[3])); \
        *reinterpret_cast<uint2*>(&Hb[(PB) ^ 1][hw]) = hv;                         \
        asm volatile("s_waitcnt lgkmcnt(0)" ::: "memory");                         \
        __builtin_amdgcn_s_barrier();                                              \
        __builtin_amdgcn_sched_barrier(0);                                         \
    }

    #pragma unroll 1
    for (int t = 0; t < SEQ; t += 2) {
        STEP(t,     0, xgA, idxA);
        STEP(t + 1, 1, xgB, idxB);
    }
#undef STEP

    // ---- final dense + sigmoid: h(79) in Hb[0]; 32 threads per batch row ----
    const char* hb0 = (const char*)&Hb[0][0];
    const int r = tid >> 5, m = tid & 31;   // r 0..15, cols 4m..4m+3
    const int fb = r * 256 + (((m >> 1) ^ r) & 15) * 16 + (m & 1) * 8;
    const uint2 hv = *reinterpret_cast<const uint2*>(hb0 + fb);
    const float4 wd = *reinterpret_cast<const float4*>(&Wd[4 * m]);
    float part = f16b2f((unsigned short)(hv.x & 0xffff)) * wd.x
               + f16b2f((unsigned short)(hv.x >> 16))    * wd.y
               + f16b2f((unsigned short)(hv.y & 0xffff)) * wd.z
               + f16b2f((unsigned short)(hv.y >> 16))    * wd.w;
    part += __shfl_down(part, 16, 32);
    part += __shfl_down(part, 8, 32);
    part += __shfl_down(part, 4, 32);
    part += __shfl_down(part, 2, 32);
    part += __shfl_down(part, 1, 32);
    if (m == 0) out[rb + r] = 1.f / (1.f + expf(-(part + bd[0])));
}

// ---------------------------------------------------------------------------
extern "C" void kernel_launch(void* const* d_in, const int* in_sizes, int n_in,
                              void* d_out, int out_size, void* d_ws, size_t ws_size,
                              hipStream_t stream)
{
    (void)in_sizes; (void)n_in; (void)out_size; (void)ws_size;
    const int*   x   = (const int*)  d_in[0];
    const float* emb = (const float*)d_in[1];
    const float* Wxh = (const float*)d_in[2];
    const float* Whh = (const float*)d_in[3];
    const float* bh  = (const float*)d_in[4];
    const float* Wd  = (const float*)d_in[5];
    const float* bd  = (const float*)d_in[6];
    float* out = (float*)d_out;

    float*    P  = (float*)d_ws;                               // 25.6 MB f32
    _Float16* W2 = (_Float16*)((char*)d_ws + 25600000);        // 80 KB

    k_wprep<<<20, 256, 0, stream>>>(Wxh, W2);
    k_ptab<<<(VOCAB + 63) / 64, 256, 0, stream>>>(emb, W2, bh, P);
    k_rnn<<<BATCH / 16, 512, 0, stream>>>(x, P, Whh, Wd, bd, out);
}

// Round 14
// 73.109 us; speedup vs baseline: 2.7399x; 1.1169x over previous
//
#include <hip/hip_runtime.h>
#include <hip/hip_fp16.h>
#include <cstdint>

#define VOCAB 50000
#define EMB   300
#define SEQ   80
#define HID   128
#define BATCH 4096

typedef __attribute__((ext_vector_type(8))) _Float16 f16x8;
typedef __attribute__((ext_vector_type(4))) float    f32x4;

static __device__ __forceinline__ float fast_tanh(float xv) {
    const float e = __expf(2.f * xv);
    float r;
    asm("v_rcp_f32 %0, %1" : "=v"(r) : "v"(e + 1.f));
    return fmaf(-2.f, r, 1.f);
}
static __device__ __forceinline__ float f16b2f(unsigned short u) {
    _Float16 h; __builtin_memcpy(&h, &u, 2); return (float)h;
}
static __device__ __forceinline__ unsigned pack2h(float a, float b) {
    _Float16 ha = (_Float16)a, hb = (_Float16)b;
    unsigned short ua, ub;
    __builtin_memcpy(&ua, &ha, 2); __builtin_memcpy(&ub, &hb, 2);
    return (unsigned)ua | ((unsigned)ub << 16);
}

// ---------------------------------------------------------------------------
// k_wprep: fragment-ordered fp16 Wxh table (for k_ptab).
//  c=(ks,col,g): W2[c][j] = Wxh[32ks+8g+j][col], zero-padded past K=300.
// ---------------------------------------------------------------------------
__global__ __launch_bounds__(256) void k_wprep(const float* __restrict__ Wxh,
                                               _Float16* __restrict__ W2) {
    const int c = blockIdx.x * 256 + threadIdx.x;
    if (c >= 5120) return;
    const int ks = c >> 9, rem = c & 511, col = rem >> 2, g = rem & 3;
    f16x8 f;
    #pragma unroll
    for (int j = 0; j < 8; ++j) {
        const int k = 32 * ks + 8 * g + j;
        f[j] = (_Float16)(k < EMB ? Wxh[k * HID + col] : 0.f);
    }
    *reinterpret_cast<f16x8*>(W2 + (size_t)c * 8) = f;
}

// ---------------------------------------------------------------------------
// k_ptab: P[v][c] = fp16( emb[v] @ Wxh + bh ), bh folded. BARRIER-FREE
// register-direct structure (R10/R13-verified), fp16 output (R7-compatible).
// 256 thr / 4 independent waves; wave owns 16 rows x ALL 128 cols; emb read
// exactly once; Wxh frags streamed from L2-resident W2, prefetched 1 tile
// ahead; P written straight from D-layout registers (uint2/lane/tile).
// ---------------------------------------------------------------------------
__global__ __launch_bounds__(256, 2) void k_ptab(
    const float*    __restrict__ emb,  // [VOCAB][300]
    const _Float16* __restrict__ W2,   // Wxh frag table
    const float*    __restrict__ bh,   // [128]
    _Float16*       __restrict__ P)    // [VOCAB][128] fp16
{
    const int tid = threadIdx.x, lane = tid & 63;
    const int wv = tid >> 6, r16 = lane & 15, g = lane >> 4;
    const int row = blockIdx.x * 64 + wv * 16 + r16;
    const float* rp = emb + (size_t)(row < VOCAB ? row : VOCAB - 1) * EMB;
    const bool wr = (row < VOCAB);

    f16x8 ef[10];
    #pragma unroll
    for (int ks = 0; ks < 9; ++ks) {
        const float4 u0 = *reinterpret_cast<const float4*>(rp + 32 * ks + 8 * g);
        const float4 u1 = *reinterpret_cast<const float4*>(rp + 32 * ks + 8 * g + 4);
        f16x8 f;
        f[0] = (_Float16)u0.x; f[1] = (_Float16)u0.y;
        f[2] = (_Float16)u0.z; f[3] = (_Float16)u0.w;
        f[4] = (_Float16)u1.x; f[5] = (_Float16)u1.y;
        f[6] = (_Float16)u1.z; f[7] = (_Float16)u1.w;
        ef[ks] = f;
    }
    {
        f16x8 f;
        #pragma unroll
        for (int j = 0; j < 8; ++j) f[j] = (_Float16)0.f;
        if (g == 0) {
            const float4 u0 = *reinterpret_cast<const float4*>(rp + 288);
            const float4 u1 = *reinterpret_cast<const float4*>(rp + 292);
            f[0] = (_Float16)u0.x; f[1] = (_Float16)u0.y;
            f[2] = (_Float16)u0.z; f[3] = (_Float16)u0.w;
            f[4] = (_Float16)u1.x; f[5] = (_Float16)u1.y;
            f[6] = (_Float16)u1.z; f[7] = (_Float16)u1.w;
        } else if (g == 1) {
            const float4 u0 = *reinterpret_cast<const float4*>(rp + 296);
            f[0] = (_Float16)u0.x; f[1] = (_Float16)u0.y;
            f[2] = (_Float16)u0.z; f[3] = (_Float16)u0.w;
        }
        ef[9] = f;
    }

    float4 bhf[8];
    #pragma unroll
    for (int ct = 0; ct < 8; ++ct)
        bhf[ct] = *reinterpret_cast<const float4*>(bh + 16 * ct + 4 * g);

    f16x8 wA[10], wB[10];
    #pragma unroll
    for (int ks = 0; ks < 10; ++ks)
        wA[ks] = *reinterpret_cast<const f16x8*>(
            W2 + ((size_t)ks * 512 + (size_t)r16 * 4 + g) * 8);

    unsigned short* const po = (unsigned short*)P + (size_t)(wr ? row : 0) * HID;

    #pragma unroll
    for (int ct = 0; ct < 8; ++ct) {
        if (ct < 7) {
            const int coln = 16 * (ct + 1) + r16;
            #pragma unroll
            for (int ks = 0; ks < 10; ++ks)
                ((ct & 1) ? wA : wB)[ks] = *reinterpret_cast<const f16x8*>(
                    W2 + ((size_t)ks * 512 + (size_t)coln * 4 + g) * 8);
        }
        const f16x8* wc = (ct & 1) ? wB : wA;
        f32x4 a0 = {0.f, 0.f, 0.f, 0.f}, a1 = {0.f, 0.f, 0.f, 0.f};
        #pragma unroll
        for (int ks = 0; ks < 10; ks += 2) {
            a0 = __builtin_amdgcn_mfma_f32_16x16x32_f16(wc[ks],     ef[ks],     a0, 0, 0, 0);
            a1 = __builtin_amdgcn_mfma_f32_16x16x32_f16(wc[ks + 1], ef[ks + 1], a1, 0, 0, 0);
        }
        uint2 o;
        o.x = pack2h(a0[0] + a1[0] + bhf[ct].x, a0[1] + a1[1] + bhf[ct].y);
        o.y = pack2h(a0[2] + a1[2] + bhf[ct].z, a0[3] + a1[3] + bhf[ct].w);
        if (wr) *reinterpret_cast<uint2*>(po + ct * 16 + g * 4) = o;
    }
}

// ---------------------------------------------------------------------------
// k_rnn: R7 VERBATIM (best measured: 1241 cyc/step / 41.4 us).
// h(t) = tanh( P[x[b,t]] + h(t-1) @ Whh ), 16 batch rows x 80 steps,
// 8 waves (2/SIMD), wave owns 16 cols. Swapped-operand MFMA (compute h^T):
//   mfma(wh[ks], h_frag[ks], acc) -> D lane (g,r16) reg r =
//   h_new[batch row r16][col 16wv+4g+r]  (4 consecutive cols)
// -> xp init = ONE ds_read_b64, h write = ONE ds_write_b64 (cvt_pk x2),
// all on the XOR-16B swizzle. One raw barrier/step (lgkm-only drain).
// ---------------------------------------------------------------------------
__global__ __launch_bounds__(512, 2) void k_rnn(
    const int*      __restrict__ x,    // [BATCH][SEQ]
    const _Float16* __restrict__ P,    // [VOCAB][128] fp16 (bh folded)
    const float*    __restrict__ Whh,  // [128][128]
    const float*    __restrict__ Wd,   // [128]
    const float*    __restrict__ bd,   // [1]
    float*          __restrict__ out)  // [BATCH]
{
    __shared__ __align__(16) unsigned char Xb[2][16 * 256];  // xp, fp16
    __shared__ __align__(16) unsigned char Hb[2][16 * 256];  // h, fp16
    __shared__ int xidx[16 * SEQ];

    const int tid = threadIdx.x, lane = tid & 63, wv = tid >> 6;
    const int r16 = lane & 15, g = lane >> 4;
    const int rb = blockIdx.x * 16;

    for (int q = tid; q < 16 * SEQ; q += 512) xidx[q] = x[rb * SEQ + q];
    if (tid < 256) { uint4 z = {}; *reinterpret_cast<uint4*>(&Hb[0][tid * 16]) = z; }

    const int col = 16 * wv + r16;

    int h_rd[4];
    #pragma unroll
    for (int ks = 0; ks < 4; ++ks)
        h_rd[ks] = r16 * 256 + (((4 * ks + g) ^ r16) & 15) * 16;
    const int hw = r16 * 256 + (((2 * wv + (g >> 1)) ^ r16) & 15) * 16 + (g & 1) * 8;

    // Whh fragments (one-time strided loads)
    f16x8 wh[4];
    #pragma unroll
    for (int ks = 0; ks < 4; ++ks) {
        f16x8 f;
        #pragma unroll
        for (int j = 0; j < 8; ++j)
            f[j] = (_Float16)Whh[(32 * ks + 8 * g + j) * HID + col];
        wh[ks] = f;
    }

    const bool gon  = (tid < 256);
    const int  grow = (tid >> 4) & 15, gk = tid & 15;
    const int  gdst = grow * 256 + ((gk ^ grow) & 15) * 16;

    __syncthreads();  // xidx + h0 ready

    if (gon)
        *reinterpret_cast<uint4*>(&Xb[0][gdst]) = *reinterpret_cast<const uint4*>(
            P + (size_t)xidx[grow * SEQ] * HID + 8 * gk);
    uint4 cur = {}, nxt = {};
    if (gon) cur = *reinterpret_cast<const uint4*>(
        P + (size_t)xidx[grow * SEQ + 1] * HID + 8 * gk);

    asm volatile("s_waitcnt lgkmcnt(0)" ::: "memory");
    __builtin_amdgcn_s_barrier();
    __builtin_amdgcn_sched_barrier(0);

#define STEP(T, PB, CUR, NXT)                                                      \
    {                                                                              \
        if ((T) + 1 < SEQ && gon)                                                  \
            *reinterpret_cast<uint4*>(&Xb[(PB) ^ 1][gdst]) = CUR;                  \
        if ((T) + 2 < SEQ && gon)                                                  \
            NXT = *reinterpret_cast<const uint4*>(                                 \
                P + (size_t)xidx[grow * SEQ + (T) + 2] * HID + 8 * gk);            \
        const uint2 xv = *reinterpret_cast<const uint2*>(&Xb[PB][hw]);             \
        f32x4 accA, accB = {0.f, 0.f, 0.f, 0.f};                                   \
        accA[0] = f16b2f((unsigned short)(xv.x & 0xffff));                         \
        accA[1] = f16b2f((unsigned short)(xv.x >> 16));                            \
        accA[2] = f16b2f((unsigned short)(xv.y & 0xffff));                         \
        accA[3] = f16b2f((unsigned short)(xv.y >> 16));                            \
        const f16x8 h0 = *reinterpret_cast<const f16x8*>(&Hb[PB][h_rd[0]]);        \
        const f16x8 h1 = *reinterpret_cast<const f16x8*>(&Hb[PB][h_rd[1]]);        \
        const f16x8 h2 = *reinterpret_cast<const f16x8*>(&Hb[PB][h_rd[2]]);        \
        const f16x8 h3 = *reinterpret_cast<const f16x8*>(&Hb[PB][h_rd[3]]);        \
        accA = __builtin_amdgcn_mfma_f32_16x16x32_f16(wh[0], h0, accA, 0, 0, 0);   \
        accB = __builtin_amdgcn_mfma_f32_16x16x32_f16(wh[1], h1, accB, 0, 0, 0);   \
        accA = __builtin_amdgcn_mfma_f32_16x16x32_f16(wh[2], h2, accA, 0, 0, 0);   \
        accB = __builtin_amdgcn_mfma_f32_16x16x32_f16(wh[3], h3, accB, 0, 0, 0);   \
        uint2 hv;                                                                  \
        hv.x = pack2h(fast_tanh(accA[0] + accB[0]), fast_tanh(accA[1] + accB[1])); \
        hv.y = pack2h(fast_tanh(accA[2] + accB[2]), fast_tanh(accA[3] + accB[3])); \
        *reinterpret_cast<uint2*>(&Hb[(PB) ^ 1][hw]) = hv;                         \
        asm volatile("s_waitcnt lgkmcnt(0)" ::: "memory");                         \
        __builtin_amdgcn_s_barrier();                                              \
        __builtin_amdgcn_sched_barrier(0);                                         \
    }

    for (int t = 0; t < SEQ; t += 2) {
        STEP(t,     0, cur, nxt);
        STEP(t + 1, 1, nxt, cur);
    }
#undef STEP

    // ---- final dense + sigmoid: h(79) in Hb[0]; 32 threads per batch row ----
    const char* hb0 = (const char*)&Hb[0][0];
    const int r = tid >> 5, m = tid & 31;   // cols 4m..4m+3
    const int fb = r * 256 + (((m >> 1) ^ r) & 15) * 16 + (m & 1) * 8;
    const uint2 hv = *reinterpret_cast<const uint2*>(hb0 + fb);
    const float4 wd = *reinterpret_cast<const float4*>(&Wd[4 * m]);
    float part = f16b2f((unsigned short)(hv.x & 0xffff)) * wd.x
               + f16b2f((unsigned short)(hv.x >> 16))    * wd.y
               + f16b2f((unsigned short)(hv.y & 0xffff)) * wd.z
               + f16b2f((unsigned short)(hv.y >> 16))    * wd.w;
    part += __shfl_down(part, 16, 32);
    part += __shfl_down(part, 8, 32);
    part += __shfl_down(part, 4, 32);
    part += __shfl_down(part, 2, 32);
    part += __shfl_down(part, 1, 32);
    if (m == 0) out[rb + r] = 1.f / (1.f + expf(-(part + bd[0])));
}

// ---------------------------------------------------------------------------
extern "C" void kernel_launch(void* const* d_in, const int* in_sizes, int n_in,
                              void* d_out, int out_size, void* d_ws, size_t ws_size,
                              hipStream_t stream)
{
    (void)in_sizes; (void)n_in; (void)out_size; (void)ws_size;
    const int*   x   = (const int*)  d_in[0];
    const float* emb = (const float*)d_in[1];
    const float* Wxh = (const float*)d_in[2];
    const float* Whh = (const float*)d_in[3];
    const float* bh  = (const float*)d_in[4];
    const float* Wd  = (const float*)d_in[5];
    const float* bd  = (const float*)d_in[6];
    float* out = (float*)d_out;

    _Float16* P  = (_Float16*)d_ws;                          // 12.8 MB fp16
    _Float16* W2 = (_Float16*)((char*)d_ws + 12800000);      // 80 KB

    k_wprep<<<20, 256, 0, stream>>>(Wxh, W2);
    k_ptab<<<(VOCAB + 63) / 64, 256, 0, stream>>>(emb, W2, bh, P);
    k_rnn<<<BATCH / 16, 512, 0, stream>>>(x, P, Whh, Wd, bd, out);
}